// Round 6
// baseline (665.465 us; speedup 1.0000x reference)
//
#include <hip/hip_runtime.h>
#include <hip/hip_bf16.h>
#include <math.h>

// Problem constants (from reference setup_inputs)
#define B_  64
#define T_  1000
#define D_  512
#define V_  29
#define L_  200
#define S_  401          // 2*L+1
#define VPAD 32          // padded stride for prob rows
#define BLANK_ 28

// ---------------------------------------------------------------------------
// Kernel 1: fused head (Linear D->V) + softmax, writes PROBS p[b][t][v] with
// stride VPAD. One 32-lane group per row (b,t); 8 rows per 256-thread block.
// Rows with t >= feature_lengths[b] are skipped (never read downstream).
// (Identical to the round-1 passing head except the write is e/se, not log.)
// ---------------------------------------------------------------------------
__global__ __launch_bounds__(256) void head_softmax_kernel(
    const float* __restrict__ feat,   // [B][T][D]
    const float* __restrict__ W,      // [D][V]
    const float* __restrict__ bias,   // [V]
    const int*   __restrict__ flen,   // [B]
    float*       __restrict__ p)      // [B][T][VPAD]
{
    __shared__ float frow[8][D_];
    const int g    = threadIdx.x >> 5;   // row group 0..7
    const int lane = threadIdx.x & 31;
    const int r    = blockIdx.x * 8 + g; // row id 0..63999
    const int b    = r / T_;
    const int t    = r - b * T_;
    const bool active = (t < flen[b]);

    if (active) {
        const float4* src = (const float4*)(feat + (size_t)r * D_);
        float4* dst = (float4*)frow[g];
        #pragma unroll
        for (int i = 0; i < 4; ++i) dst[lane + 32 * i] = src[lane + 32 * i];
    }
    __syncthreads();

    if (active) {
        float logit = -1e30f;
        if (lane < V_) {
            float a0 = bias[lane], a1 = 0.f, a2 = 0.f, a3 = 0.f;
            const float* w = W + lane;
            #pragma unroll 8
            for (int d = 0; d < D_; d += 4) {
                a0 += frow[g][d]     * w[(size_t)d * V_];
                a1 += frow[g][d + 1] * w[(size_t)(d + 1) * V_];
                a2 += frow[g][d + 2] * w[(size_t)(d + 2) * V_];
                a3 += frow[g][d + 3] * w[(size_t)(d + 3) * V_];
            }
            logit = (a0 + a1) + (a2 + a3);
        }
        float mx = logit;
        #pragma unroll
        for (int off = 16; off; off >>= 1)
            mx = fmaxf(mx, __shfl_xor(mx, off, 32));
        float e = (lane < V_) ? __expf(logit - mx) : 0.f;
        float se = e;
        #pragma unroll
        for (int off = 16; off; off >>= 1)
            se += __shfl_xor(se, off, 32);
        if (lane < V_)
            p[(size_t)r * VPAD + lane] = e / se;   // softmax prob
    }
}

// ---------------------------------------------------------------------------
// Kernel 2: CTC alpha recursion, linear probability space with PER-LANE
// block-floating-point scaling. One 64-lane wave per sample; lane l owns 7
// contiguous states in registers r[7] plus a log2-scale c:
//     true alpha[s] = r[k] * 2^(c - 60)
// Per step the lane max is renormalized to 2^60, so each lane has ~129 nats
// of usable range below ITS OWN local max (the global spread across s, which
// killed the single-scale version, lives in the per-lane c's, exact in f32).
// Cross-lane terms are rescaled by 2^(c_{l-1} - c') with c' = max(c, c_{l-1})
// (exponents <= 0: can only underflow, which is then genuinely negligible).
// Dead lanes adopt the neighbor's scale through the max, so the advancing
// front enters at factor 2^0. No barriers; 3 transcendental ops per step.
// NOTE: exp2f/log2f (NOT __exp2f/__log2f — those collide with glibc math.h
// internals at device compile); on gfx950 they lower to v_exp_f32/v_log_f32.
// ---------------------------------------------------------------------------
__device__ __forceinline__ float wave_shr1_zero(float x) {
    // lane l gets lane l-1's value; lane 0 gets 0.0f
    return __int_as_float(__builtin_amdgcn_update_dpp(
        0, __float_as_int(x), 0x138 /*wave_shr:1*/, 0xf, 0xf, true));
}
__device__ __forceinline__ float wave_shr1_self(float x) {
    // lane l gets lane l-1's value; lane 0 keeps its own x
    return __int_as_float(__builtin_amdgcn_update_dpp(
        __float_as_int(x), __float_as_int(x), 0x138 /*wave_shr:1*/, 0xf, 0xf, false));
}
__device__ __forceinline__ float bperm(int byte_addr, float v) {
    return __int_as_float(__builtin_amdgcn_ds_bpermute(byte_addr, __float_as_int(v)));
}

#define TWO60  1.152921504606846976e18f   // 2^60
#define TWOM60 8.673617379884035e-19f     // 2^-60
#define NEGLOG2 (-1.5e9f)                 // log2-domain stand-in for -inf

__global__ __launch_bounds__(64) void ctc_alpha_bfp_kernel(
    const float* __restrict__ p,      // [B][T][VPAD] probs
    const int*   __restrict__ labels, // [B][L]
    const int*   __restrict__ flen,   // [B]
    const int*   __restrict__ llen,   // [B]
    float*       __restrict__ nll)    // [B]
{
    const int b    = blockIdx.x;
    const int lane = threadIdx.x;     // 0..63
    const float* pb = p + (size_t)b * T_ * VPAD;
    const int Tb = flen[b];
    const int ll = llen[b];

    // Per-lane static trellis data for states s = 7*lane + k
    int   off4[7];
    float allowf[7];
    #pragma unroll
    for (int k = 0; k < 7; ++k) {
        int s = 7 * lane + k;
        int o = 29;                 // invalid state -> reads lane 29 (always 0)
        float al = 0.f;
        if (s < S_) {
            if (s & 1) {
                int li = (s - 1) >> 1;
                o = labels[b * L_ + li];
                if (s >= 3) al = (o != labels[b * L_ + li - 1]) ? 1.f : 0.f;
            } else {
                o = BLANK_;
            }
        }
        off4[k]   = o << 2;
        allowf[k] = al;
    }

    // t = 0 init: alpha[0][s] = p0[ext[s]] for s in {0,1}, else 0. Scale c=0.
    float p29 = (lane < V_) ? pb[lane] : 0.f;
    float r[7];
    float c = 0.f;
    #pragma unroll
    for (int k = 0; k < 7; ++k) {
        float q = bperm(off4[k], p29);
        r[k] = (lane == 0 && k < 2) ? q * TWO60 : 0.f;
    }

    // prob-row prefetch pipeline, depth 2
    float pc = (Tb > 1 && lane < V_) ? pb[VPAD + lane]     : 0.f;  // row 1
    float pn = (Tb > 2 && lane < V_) ? pb[2 * VPAD + lane] : 0.f;  // row 2

    for (int t = 1; t < Tb; ++t) {
        float pf = ((t + 2) < Tb && lane < V_) ? pb[(size_t)(t + 2) * VPAD + lane] : 0.f;

        // distribute this step's probs to states
        float q[7];
        #pragma unroll
        for (int k = 0; k < 7; ++k) q[k] = bperm(off4[k], pc);

        // cross-lane neighbors (previous alpha) + neighbor scale
        float u1 = wave_shr1_zero(r[6]);   // state 7l-1
        float u2 = wave_shr1_zero(r[5]);   // state 7l-2
        float cp = wave_shr1_self(c);      // c_{l-1} (lane 0: own c)

        // reconcile scales: c' = max(c, cp); factors <= 1 by construction
        float cm = fmaxf(c, cp);
        float fs = exp2f(c  - cm);
        float fu = exp2f(cp - cm);
        u1 *= fu; u2 *= fu;
        #pragma unroll
        for (int k = 0; k < 7; ++k) r[k] *= fs;

        float nr[7];
        nr[0] = q[0] * (r[0] + u1   + allowf[0] * u2);
        nr[1] = q[1] * (r[1] + r[0] + allowf[1] * u1);
        #pragma unroll
        for (int k = 2; k < 7; ++k)
            nr[k] = q[k] * (r[k] + r[k - 1] + allowf[k] * r[k - 2]);

        // renormalize lane max to 2^60; clamp keeps inv finite (<= ~2^120)
        float m = nr[0];
        #pragma unroll
        for (int k = 1; k < 7; ++k) m = fmaxf(m, nr[k]);
        m = fmaxf(m, TWOM60);
        float lm  = log2f(m);
        float inv = __builtin_amdgcn_rcpf(m) * TWO60;
        #pragma unroll
        for (int k = 0; k < 7; ++k) r[k] = nr[k] * inv;
        c = cm + (lm - 60.0f);

        pc = pn; pn = pf;
    }

    // final readout: per-state true log2(alpha), then logaddexp2 of the two
    // terminal states, convert to nats.
    __shared__ float fin[448];
    #pragma unroll
    for (int k = 0; k < 7; ++k) {
        float v = r[k];
        fin[7 * lane + k] = (v > 0.f) ? (c + (log2f(v) - 60.0f)) : NEGLOG2;
    }
    __syncthreads();
    if (lane == 0) {
        int ib = 2 * ll;                       // <= 400
        float l1 = fin[ib];
        float l2 = (ll > 0) ? fin[ib - 1] : NEGLOG2;
        float mm = fmaxf(l1, l2);
        float s2 = exp2f(l1 - mm) + exp2f(l2 - mm);
        float nl = -0.6931471805599453f * (mm + log2f(s2));
        // zero_infinity + mean-by-target-length semantics
        nll[b] = (nl < 5e8f) ? nl / fmaxf((float)ll, 1.f) : 0.f;
    }
}

// ---------------------------------------------------------------------------
// Kernel 3: mean over B=64 per-sample losses -> scalar
// ---------------------------------------------------------------------------
__global__ __launch_bounds__(64) void reduce_mean_kernel(
    const float* __restrict__ nll, float* __restrict__ out)
{
    float v = nll[threadIdx.x];
    #pragma unroll
    for (int off = 32; off; off >>= 1) v += __shfl_down(v, off);
    if (threadIdx.x == 0) out[0] = v * (1.0f / (float)B_);
}

// ---------------------------------------------------------------------------
extern "C" void kernel_launch(void* const* d_in, const int* in_sizes, int n_in,
                              void* d_out, int out_size, void* d_ws, size_t ws_size,
                              hipStream_t stream) {
    const float* feat   = (const float*)d_in[0];  // [64,1000,512] f32
    const float* W      = (const float*)d_in[1];  // [512,29] f32
    const float* bias   = (const float*)d_in[2];  // [29] f32
    const int*   labels = (const int*)  d_in[3];  // [64,200] i32
    const int*   flen   = (const int*)  d_in[4];  // [64] i32
    const int*   llen   = (const int*)  d_in[5];  // [64] i32
    float* out = (float*)d_out;

    float* p   = (float*)d_ws;                                    // 8.192 MB
    float* nll = (float*)((char*)d_ws + (size_t)8 * 1024 * 1024); // B floats

    head_softmax_kernel<<<(B_ * T_) / 8, 256, 0, stream>>>(feat, W, bias, flen, p);
    ctc_alpha_bfp_kernel<<<B_, 64, 0, stream>>>(p, labels, flen, llen, nll);
    reduce_mean_kernel<<<1, 64, 0, stream>>>(nll, out);
}

// Round 8
// 426.343 us; speedup vs baseline: 1.5609x; 1.5609x over previous
//
#include <hip/hip_runtime.h>
#include <hip/hip_bf16.h>
#include <math.h>

// Problem constants (from reference setup_inputs)
#define B_  64
#define T_  1000
#define D_  512
#define V_  29
#define L_  200
#define S_  401          // 2*L+1
#define VPAD 32          // padded stride for prob rows
#define BLANK_ 28

// ---------------------------------------------------------------------------
// Kernel 1: fused head (Linear D->V) + softmax, writes PROBS p[b][t][v] with
// stride VPAD. One 32-lane group per row (b,t); 8 rows per 256-thread block.
// Rows with t >= feature_lengths[b] are skipped (never read downstream).
// Pad columns 29..31 are ZEROED (trellis reads them directly for dead states).
// ---------------------------------------------------------------------------
__global__ __launch_bounds__(256) void head_softmax_kernel(
    const float* __restrict__ feat,   // [B][T][D]
    const float* __restrict__ W,      // [D][V]
    const float* __restrict__ bias,   // [V]
    const int*   __restrict__ flen,   // [B]
    float*       __restrict__ p)      // [B][T][VPAD]
{
    __shared__ float frow[8][D_];
    const int g    = threadIdx.x >> 5;   // row group 0..7
    const int lane = threadIdx.x & 31;
    const int r    = blockIdx.x * 8 + g; // row id 0..63999
    const int b    = r / T_;
    const int t    = r - b * T_;
    const bool active = (t < flen[b]);

    if (active) {
        const float4* src = (const float4*)(feat + (size_t)r * D_);
        float4* dst = (float4*)frow[g];
        #pragma unroll
        for (int i = 0; i < 4; ++i) dst[lane + 32 * i] = src[lane + 32 * i];
    }
    __syncthreads();

    if (active) {
        float logit = -1e30f;
        if (lane < V_) {
            float a0 = bias[lane], a1 = 0.f, a2 = 0.f, a3 = 0.f;
            const float* w = W + lane;
            #pragma unroll 8
            for (int d = 0; d < D_; d += 4) {
                a0 += frow[g][d]     * w[(size_t)d * V_];
                a1 += frow[g][d + 1] * w[(size_t)(d + 1) * V_];
                a2 += frow[g][d + 2] * w[(size_t)(d + 2) * V_];
                a3 += frow[g][d + 3] * w[(size_t)(d + 3) * V_];
            }
            logit = (a0 + a1) + (a2 + a3);
        }
        float mx = logit;
        #pragma unroll
        for (int off = 16; off; off >>= 1)
            mx = fmaxf(mx, __shfl_xor(mx, off, 32));
        float e = (lane < V_) ? __expf(logit - mx) : 0.f;
        float se = e;
        #pragma unroll
        for (int off = 16; off; off >>= 1)
            se += __shfl_xor(se, off, 32);
        p[(size_t)r * VPAD + lane] = (lane < V_) ? e / se : 0.f;
    }
}

// ---------------------------------------------------------------------------
// Kernel 2: CTC alpha recursion, linear space, per-lane INTEGER power-of-2
// scaling (exact), p-slice staged in LDS.
//   invariant: true alpha[7*lane+k] = r[k] * 2^c   (c per-lane int)
// Per step: renormalize lane max into [2^60, 2^61) via exponent-field bit
// ops (no transcendentals, no rcp — exact). Cross-lane neighbors rescaled by
// 2^(c_nb - max) with factors built by bit-twiddling (underflow-only).
// q values come from LDS (whole 128KB p-slice staged once by 256 threads),
// prefetched 2 steps ahead in named register buffers. No barriers in loop.
// Round-6 proven logic; only the scale representation + q source changed.
// ---------------------------------------------------------------------------
__device__ __forceinline__ float wave_shr1_zero(float x) {
    // lane l gets lane l-1's value; lane 0 gets 0.0f
    return __int_as_float(__builtin_amdgcn_update_dpp(
        0, __float_as_int(x), 0x138 /*wave_shr:1*/, 0xf, 0xf, true));
}
__device__ __forceinline__ int shr1_self_i(int x) {
    // lane l gets lane l-1's value; lane 0 keeps its own x
    return __builtin_amdgcn_update_dpp(x, x, 0x138 /*wave_shr:1*/, 0xf, 0xf, false);
}

#define TWO60  1.152921504606846976e18f   // 2^60
#define TWOM60 8.673617379884035e-19f     // 2^-60
#define NEGLOG2 (-1.5e9f)                 // log2-domain stand-in for -inf

// one trellis step consuming prob regs Q[0..6]; updates r[], c
#define CTC_STEP(Q) do {                                                      \
    int   cp = shr1_self_i(c);                                                \
    float u1 = wave_shr1_zero(r[6]);                                          \
    float u2 = wave_shr1_zero(r[5]);                                          \
    int   cm = (c > cp) ? c : cp;                                             \
    int   dc = c  - cm; if (dc < -127) dc = -127;                             \
    int   dp = cp - cm; if (dp < -127) dp = -127;                             \
    float fs = __int_as_float((dc + 127) << 23);                              \
    float fu = __int_as_float((dp + 127) << 23);                              \
    u1 *= fu; u2 *= fu;                                                       \
    float s0 = r[0]*fs, s1 = r[1]*fs, s2 = r[2]*fs, s3 = r[3]*fs;             \
    float s4 = r[4]*fs, s5 = r[5]*fs, s6 = r[6]*fs;                           \
    float n0 = Q[0] * (s0 + u1 + allowf[0] * u2);                             \
    float n1 = Q[1] * (s1 + s0 + allowf[1] * u1);                             \
    float n2 = Q[2] * (s2 + s1 + allowf[2] * s0);                             \
    float n3 = Q[3] * (s3 + s2 + allowf[3] * s1);                             \
    float n4 = Q[4] * (s4 + s3 + allowf[4] * s2);                             \
    float n5 = Q[5] * (s5 + s4 + allowf[5] * s3);                             \
    float n6 = Q[6] * (s6 + s5 + allowf[6] * s4);                             \
    float m  = fmaxf(fmaxf(fmaxf(n0, n1), fmaxf(n2, n3)),                     \
                     fmaxf(fmaxf(n4, n5), n6));                               \
    m = fmaxf(m, TWOM60);                                                     \
    int e   = (__float_as_int(m) >> 23) - 127;  /* floor(log2(m)) */          \
    float sc = __int_as_float((187 - e) << 23); /* 2^(60-e), exact */         \
    r[0]=n0*sc; r[1]=n1*sc; r[2]=n2*sc; r[3]=n3*sc;                           \
    r[4]=n4*sc; r[5]=n5*sc; r[6]=n6*sc;                                       \
    c = cm + e - 60;                                                          \
} while (0)

#define PREFETCH(Q, row) do {                                                 \
    int _base = (row) * VPAD;                                                 \
    Q[0]=plds[_base+oi[0]]; Q[1]=plds[_base+oi[1]]; Q[2]=plds[_base+oi[2]];   \
    Q[3]=plds[_base+oi[3]]; Q[4]=plds[_base+oi[4]]; Q[5]=plds[_base+oi[5]];   \
    Q[6]=plds[_base+oi[6]];                                                   \
} while (0)

__global__ __launch_bounds__(256) void ctc_alpha_lds_kernel(
    const float* __restrict__ p,      // [B][T][VPAD] probs
    const int*   __restrict__ labels, // [B][L]
    const int*   __restrict__ flen,   // [B]
    const int*   __restrict__ llen,   // [B]
    float*       __restrict__ nll)    // [B]
{
    __shared__ float plds[T_ * VPAD];           // 128 KB: whole p-slice
    const int b   = blockIdx.x;
    const int tid = threadIdx.x;
    const float* pb = p + (size_t)b * T_ * VPAD;
    const int Tb = flen[b];
    const int ll = llen[b];

    // ---- phase 1: cooperative global->LDS copy of rows [0, Tb) ----
    {
        const float4* src4 = (const float4*)pb;
        float4* dst4 = (float4*)plds;
        const int n4 = Tb * (VPAD / 4);
        for (int i = tid; i < n4; i += 256) dst4[i] = src4[i];
    }
    __syncthreads();

    if (tid < 64) {
        const int lane = tid;

        // per-lane static trellis data for states s = 7*lane + k
        int   oi[7];
        float allowf[7];
        #pragma unroll
        for (int k = 0; k < 7; ++k) {
            int s = 7 * lane + k;
            int o = 29;             // invalid state -> zeroed pad column
            float al = 0.f;
            if (s < S_) {
                if (s & 1) {
                    int li = (s - 1) >> 1;
                    o = labels[b * L_ + li];
                    if (s >= 3) al = (o != labels[b * L_ + li - 1]) ? 1.f : 0.f;
                } else {
                    o = BLANK_;
                }
            }
            oi[k]     = o;
            allowf[k] = al;
        }

        // t = 0 init: alpha = p0[ext[s]] for s in {0,1}, else 0; c = -60
        float r[7];
        int   c = -60;
        {
            float q0[7];
            PREFETCH(q0, 0);
            #pragma unroll
            for (int k = 0; k < 7; ++k)
                r[k] = (lane == 0 && k < 2) ? q0[k] * TWO60 : 0.f;
        }

        // q prefetch, depth 2, named buffers (Tb >= 500 so rows 1,2 valid)
        float qA[7], qB[7], qN1[7], qN2[7];
        PREFETCH(qA, 1);
        PREFETCH(qB, 2);
        const int Tbm1 = Tb - 1;

        int t = 1;
        for (; t + 1 < Tb; t += 2) {
            int rowA = t + 2; if (rowA > Tbm1) rowA = Tbm1;
            int rowB = t + 3; if (rowB > Tbm1) rowB = Tbm1;
            PREFETCH(qN1, rowA);            // lands during the two steps
            CTC_STEP(qA);
            PREFETCH(qN2, rowB);
            CTC_STEP(qB);
            #pragma unroll
            for (int k = 0; k < 7; ++k) { qA[k] = qN1[k]; qB[k] = qN2[k]; }
        }
        if (t < Tb) CTC_STEP(qA);           // Tb even: one leftover step

        // per-state log2(alpha) into reused LDS
        #pragma unroll
        for (int k = 0; k < 7; ++k) {
            float v = r[k];
            plds[7 * lane + k] = (v > 0.f) ? ((float)c + log2f(v)) : NEGLOG2;
        }
    }
    __syncthreads();

    if (tid == 0) {
        int ib = 2 * ll;                    // <= 400
        float l1 = plds[ib];
        float l2 = (ll > 0) ? plds[ib - 1] : NEGLOG2;
        float mm = fmaxf(l1, l2);
        float s2 = exp2f(l1 - mm) + exp2f(l2 - mm);
        float nl = -0.6931471805599453f * (mm + log2f(s2));
        // zero_infinity + mean-by-target-length semantics
        nll[b] = (nl < 5e8f) ? nl / fmaxf((float)ll, 1.f) : 0.f;
    }
}

// ---------------------------------------------------------------------------
// Kernel 3: mean over B=64 per-sample losses -> scalar
// ---------------------------------------------------------------------------
__global__ __launch_bounds__(64) void reduce_mean_kernel(
    const float* __restrict__ nll, float* __restrict__ out)
{
    float v = nll[threadIdx.x];
    #pragma unroll
    for (int off = 32; off; off >>= 1) v += __shfl_down(v, off);
    if (threadIdx.x == 0) out[0] = v * (1.0f / (float)B_);
}

// ---------------------------------------------------------------------------
extern "C" void kernel_launch(void* const* d_in, const int* in_sizes, int n_in,
                              void* d_out, int out_size, void* d_ws, size_t ws_size,
                              hipStream_t stream) {
    const float* feat   = (const float*)d_in[0];  // [64,1000,512] f32
    const float* W      = (const float*)d_in[1];  // [512,29] f32
    const float* bias   = (const float*)d_in[2];  // [29] f32
    const int*   labels = (const int*)  d_in[3];  // [64,200] i32
    const int*   flen   = (const int*)  d_in[4];  // [64] i32
    const int*   llen   = (const int*)  d_in[5];  // [64] i32
    float* out = (float*)d_out;

    float* p   = (float*)d_ws;                                    // 8.192 MB
    float* nll = (float*)((char*)d_ws + (size_t)8 * 1024 * 1024); // B floats

    head_softmax_kernel<<<(B_ * T_) / 8, 256, 0, stream>>>(feat, W, bias, flen, p);
    ctc_alpha_lds_kernel<<<B_, 256, 0, stream>>>(p, labels, flen, llen, nll);
    reduce_mean_kernel<<<1, 64, 0, stream>>>(nll, out);
}

// Round 9
// 361.354 us; speedup vs baseline: 1.8416x; 1.1798x over previous
//
#include <hip/hip_runtime.h>
#include <hip/hip_bf16.h>
#include <math.h>

// Problem constants (from reference setup_inputs)
#define B_  64
#define T_  1000
#define D_  512
#define V_  29
#define L_  200
#define S_  401          // 2*L+1
#define VPAD 32          // padded stride for prob rows
#define BLANK_ 28

typedef __attribute__((ext_vector_type(8))) short short8v;   // 8 bf16 (4 VGPRs)
typedef __attribute__((ext_vector_type(4))) float float4v;   // MFMA acc

// f32 -> bf16 bits, round-to-nearest-even (finite inputs)
__device__ __forceinline__ unsigned short f2bf(float f) {
    unsigned int u = __float_as_uint(f);
    return (unsigned short)((u + 0x7FFFu + ((u >> 16) & 1u)) >> 16);
}

// ---------------------------------------------------------------------------
// Kernel 1: head GEMM (Linear D->V) via bf16 MFMA + fused softmax.
// One 64-lane wave per 16-row tile: 16 k-steps x 2 N-tiles of
// mfma_f32_16x16x32_bf16. A-frag: lane l holds feat[r0 + (l&15)][k], with
// k = ks*32 + (l>>4)*8 + j (rows of 4 lanes cover 128B contiguous -> fully
// coalesced). B-frags (W as bf16) pre-packed once per block into LDS, read
// as ds_read_b128. C layout (m89-verified): col = l&15, row = (l>>4)*4+reg.
// Softmax over v in-register: 16-lane shfl_xor reductions; pad cols 29..31
// written as 0 (trellis reads them). Tiles with all rows >= flen skipped.
// ---------------------------------------------------------------------------
__global__ __launch_bounds__(256) void head_mfma_softmax_kernel(
    const float* __restrict__ feat,   // [B][T][D]
    const float* __restrict__ W,      // [D][V]
    const float* __restrict__ bias,   // [V]
    const int*   __restrict__ flen,   // [B]
    float*       __restrict__ p)      // [B][T][VPAD]
{
    __shared__ uint4 bfrag_lds[16 * 2 * 64];   // 32 KB: [kstep][ntile][lane]
    const int tid = threadIdx.x;

    // ---- stage W as bf16 B-fragments (once per block) ----
    for (int f = tid; f < 2048; f += 256) {
        int ks  = f >> 7;
        int rem = f & 127;
        int tl  = rem >> 6;
        int ln  = rem & 63;
        int k0  = ks * 32 + (ln >> 4) * 8;
        int col = tl * 16 + (ln & 15);
        unsigned short h[8];
        #pragma unroll
        for (int j = 0; j < 8; ++j) {
            float wv = (col < V_) ? W[(size_t)(k0 + j) * V_ + col] : 0.f;
            h[j] = f2bf(wv);
        }
        uint4 pk;
        pk.x = h[0] | ((unsigned)h[1] << 16);
        pk.y = h[2] | ((unsigned)h[3] << 16);
        pk.z = h[4] | ((unsigned)h[5] << 16);
        pk.w = h[6] | ((unsigned)h[7] << 16);
        bfrag_lds[f] = pk;
    }
    __syncthreads();

    const int wv  = tid >> 6;        // wave 0..3
    const int l   = tid & 63;
    const int c0  = l & 15;
    const int grp = l >> 4;
    const float bias0 = bias[c0];
    const bool  v1ok  = (c0 + 16) < V_;
    const float bias1 = v1ok ? bias[c0 + 16] : 0.f;

    #pragma unroll
    for (int ti = 0; ti < 2; ++ti) {
        const int tile = (blockIdx.x * 4 + wv) * 2 + ti;  // 0..3999
        const int r0   = tile * 16;
        // skip tiles whose 16 rows are all past their sample's feature_len
        const int b0 = r0 / T_;
        const bool active = ((r0 - b0 * T_) < flen[b0]) || ((r0 + 15) / T_ != b0);
        if (!active) continue;

        const float* abase = feat + (size_t)(r0 + c0) * D_ + grp * 8;
        float4v acc0 = {0.f, 0.f, 0.f, 0.f};
        float4v acc1 = {0.f, 0.f, 0.f, 0.f};

        #pragma unroll 4
        for (int ks = 0; ks < 16; ++ks) {
            float4 fa = *(const float4*)(abase + ks * 32);
            float4 fb = *(const float4*)(abase + ks * 32 + 4);
            short8v a;
            a[0] = (short)f2bf(fa.x); a[1] = (short)f2bf(fa.y);
            a[2] = (short)f2bf(fa.z); a[3] = (short)f2bf(fa.w);
            a[4] = (short)f2bf(fb.x); a[5] = (short)f2bf(fb.y);
            a[6] = (short)f2bf(fb.z); a[7] = (short)f2bf(fb.w);
            uint4 b0v = bfrag_lds[(ks * 2 + 0) * 64 + l];
            uint4 b1v = bfrag_lds[(ks * 2 + 1) * 64 + l];
            acc0 = __builtin_amdgcn_mfma_f32_16x16x32_bf16(
                       a, __builtin_bit_cast(short8v, b0v), acc0, 0, 0, 0);
            acc1 = __builtin_amdgcn_mfma_f32_16x16x32_bf16(
                       a, __builtin_bit_cast(short8v, b1v), acc1, 0, 0, 0);
        }

        // fused bias + softmax + store (per acc reg = one row)
        #pragma unroll
        for (int j = 0; j < 4; ++j) {
            float lg0 = acc0[j] + bias0;
            float lg1 = v1ok ? (acc1[j] + bias1) : -1e30f;
            float m = fmaxf(lg0, lg1);
            #pragma unroll
            for (int off = 1; off <= 8; off <<= 1)
                m = fmaxf(m, __shfl_xor(m, off));
            float e0 = __expf(lg0 - m);
            float e1 = v1ok ? __expf(lg1 - m) : 0.f;
            float s = e0 + e1;
            #pragma unroll
            for (int off = 1; off <= 8; off <<= 1)
                s += __shfl_xor(s, off);
            float invs = 1.f / s;
            int r = r0 + grp * 4 + j;
            p[(size_t)r * VPAD + c0]      = e0 * invs;
            p[(size_t)r * VPAD + c0 + 16] = e1 * invs;   // cols 29..31 -> 0
        }
    }
}

// ---------------------------------------------------------------------------
// Kernel 2: CTC alpha recursion, linear space, per-lane INTEGER power-of-2
// scaling (exact), p-slice staged in LDS. (Unchanged from round 8: proven,
// 167 us.)  invariant: true alpha[7*lane+k] = r[k] * 2^c  (c per-lane int)
// ---------------------------------------------------------------------------
__device__ __forceinline__ float wave_shr1_zero(float x) {
    return __int_as_float(__builtin_amdgcn_update_dpp(
        0, __float_as_int(x), 0x138 /*wave_shr:1*/, 0xf, 0xf, true));
}
__device__ __forceinline__ int shr1_self_i(int x) {
    return __builtin_amdgcn_update_dpp(x, x, 0x138 /*wave_shr:1*/, 0xf, 0xf, false);
}

#define TWO60  1.152921504606846976e18f   // 2^60
#define TWOM60 8.673617379884035e-19f     // 2^-60
#define NEGLOG2 (-1.5e9f)                 // log2-domain stand-in for -inf

#define CTC_STEP(Q) do {                                                      \
    int   cp = shr1_self_i(c);                                                \
    float u1 = wave_shr1_zero(r[6]);                                          \
    float u2 = wave_shr1_zero(r[5]);                                          \
    int   cm = (c > cp) ? c : cp;                                             \
    int   dc = c  - cm; if (dc < -127) dc = -127;                             \
    int   dp = cp - cm; if (dp < -127) dp = -127;                             \
    float fs = __int_as_float((dc + 127) << 23);                              \
    float fu = __int_as_float((dp + 127) << 23);                              \
    u1 *= fu; u2 *= fu;                                                       \
    float s0 = r[0]*fs, s1 = r[1]*fs, s2 = r[2]*fs, s3 = r[3]*fs;             \
    float s4 = r[4]*fs, s5 = r[5]*fs, s6 = r[6]*fs;                           \
    float n0 = Q[0] * (s0 + u1 + allowf[0] * u2);                             \
    float n1 = Q[1] * (s1 + s0 + allowf[1] * u1);                             \
    float n2 = Q[2] * (s2 + s1 + allowf[2] * s0);                             \
    float n3 = Q[3] * (s3 + s2 + allowf[3] * s1);                             \
    float n4 = Q[4] * (s4 + s3 + allowf[4] * s2);                             \
    float n5 = Q[5] * (s5 + s4 + allowf[5] * s3);                             \
    float n6 = Q[6] * (s6 + s5 + allowf[6] * s4);                             \
    float m  = fmaxf(fmaxf(fmaxf(n0, n1), fmaxf(n2, n3)),                     \
                     fmaxf(fmaxf(n4, n5), n6));                               \
    m = fmaxf(m, TWOM60);                                                     \
    int e   = (__float_as_int(m) >> 23) - 127;  /* floor(log2(m)) */          \
    float sc = __int_as_float((187 - e) << 23); /* 2^(60-e), exact */         \
    r[0]=n0*sc; r[1]=n1*sc; r[2]=n2*sc; r[3]=n3*sc;                           \
    r[4]=n4*sc; r[5]=n5*sc; r[6]=n6*sc;                                       \
    c = cm + e - 60;                                                          \
} while (0)

#define PREFETCH(Q, row) do {                                                 \
    int _base = (row) * VPAD;                                                 \
    Q[0]=plds[_base+oi[0]]; Q[1]=plds[_base+oi[1]]; Q[2]=plds[_base+oi[2]];   \
    Q[3]=plds[_base+oi[3]]; Q[4]=plds[_base+oi[4]]; Q[5]=plds[_base+oi[5]];   \
    Q[6]=plds[_base+oi[6]];                                                   \
} while (0)

__global__ __launch_bounds__(256) void ctc_alpha_lds_kernel(
    const float* __restrict__ p,      // [B][T][VPAD] probs
    const int*   __restrict__ labels, // [B][L]
    const int*   __restrict__ flen,   // [B]
    const int*   __restrict__ llen,   // [B]
    float*       __restrict__ nll)    // [B]
{
    __shared__ float plds[T_ * VPAD];           // 128 KB: whole p-slice
    const int b   = blockIdx.x;
    const int tid = threadIdx.x;
    const float* pb = p + (size_t)b * T_ * VPAD;
    const int Tb = flen[b];
    const int ll = llen[b];

    // ---- phase 1: cooperative global->LDS copy of rows [0, Tb) ----
    {
        const float4* src4 = (const float4*)pb;
        float4* dst4 = (float4*)plds;
        const int n4 = Tb * (VPAD / 4);
        for (int i = tid; i < n4; i += 256) dst4[i] = src4[i];
    }
    __syncthreads();

    if (tid < 64) {
        const int lane = tid;

        int   oi[7];
        float allowf[7];
        #pragma unroll
        for (int k = 0; k < 7; ++k) {
            int s = 7 * lane + k;
            int o = 29;             // invalid state -> zeroed pad column
            float al = 0.f;
            if (s < S_) {
                if (s & 1) {
                    int li = (s - 1) >> 1;
                    o = labels[b * L_ + li];
                    if (s >= 3) al = (o != labels[b * L_ + li - 1]) ? 1.f : 0.f;
                } else {
                    o = BLANK_;
                }
            }
            oi[k]     = o;
            allowf[k] = al;
        }

        float r[7];
        int   c = -60;
        {
            float q0[7];
            PREFETCH(q0, 0);
            #pragma unroll
            for (int k = 0; k < 7; ++k)
                r[k] = (lane == 0 && k < 2) ? q0[k] * TWO60 : 0.f;
        }

        float qA[7], qB[7], qN1[7], qN2[7];
        PREFETCH(qA, 1);
        PREFETCH(qB, 2);
        const int Tbm1 = Tb - 1;

        int t = 1;
        for (; t + 1 < Tb; t += 2) {
            int rowA = t + 2; if (rowA > Tbm1) rowA = Tbm1;
            int rowB = t + 3; if (rowB > Tbm1) rowB = Tbm1;
            PREFETCH(qN1, rowA);
            CTC_STEP(qA);
            PREFETCH(qN2, rowB);
            CTC_STEP(qB);
            #pragma unroll
            for (int k = 0; k < 7; ++k) { qA[k] = qN1[k]; qB[k] = qN2[k]; }
        }
        if (t < Tb) CTC_STEP(qA);

        #pragma unroll
        for (int k = 0; k < 7; ++k) {
            float v = r[k];
            plds[7 * lane + k] = (v > 0.f) ? ((float)c + log2f(v)) : NEGLOG2;
        }
    }
    __syncthreads();

    if (tid == 0) {
        int ib = 2 * ll;                    // <= 400
        float l1 = plds[ib];
        float l2 = (ll > 0) ? plds[ib - 1] : NEGLOG2;
        float mm = fmaxf(l1, l2);
        float s2 = exp2f(l1 - mm) + exp2f(l2 - mm);
        float nl = -0.6931471805599453f * (mm + log2f(s2));
        nll[b] = (nl < 5e8f) ? nl / fmaxf((float)ll, 1.f) : 0.f;
    }
}

// ---------------------------------------------------------------------------
// Kernel 3: mean over B=64 per-sample losses -> scalar
// ---------------------------------------------------------------------------
__global__ __launch_bounds__(64) void reduce_mean_kernel(
    const float* __restrict__ nll, float* __restrict__ out)
{
    float v = nll[threadIdx.x];
    #pragma unroll
    for (int off = 32; off; off >>= 1) v += __shfl_down(v, off);
    if (threadIdx.x == 0) out[0] = v * (1.0f / (float)B_);
}

// ---------------------------------------------------------------------------
extern "C" void kernel_launch(void* const* d_in, const int* in_sizes, int n_in,
                              void* d_out, int out_size, void* d_ws, size_t ws_size,
                              hipStream_t stream) {
    const float* feat   = (const float*)d_in[0];  // [64,1000,512] f32
    const float* W      = (const float*)d_in[1];  // [512,29] f32
    const float* bias   = (const float*)d_in[2];  // [29] f32
    const int*   labels = (const int*)  d_in[3];  // [64,200] i32
    const int*   flen   = (const int*)  d_in[4];  // [64] i32
    const int*   llen   = (const int*)  d_in[5];  // [64] i32
    float* out = (float*)d_out;

    float* p   = (float*)d_ws;                                    // 8.192 MB
    float* nll = (float*)((char*)d_ws + (size_t)8 * 1024 * 1024); // B floats

    head_mfma_softmax_kernel<<<500, 256, 0, stream>>>(feat, W, bias, flen, p);
    ctc_alpha_lds_kernel<<<B_, 256, 0, stream>>>(p, labels, flen, llen, nll);
    reduce_mean_kernel<<<1, 64, 0, stream>>>(nll, out);
}